// Round 1
// baseline (202.974 us; speedup 1.0000x reference)
//
#include <hip/hip_runtime.h>
#include <stdint.h>

// Problem constants: x (128,16,16,16,8,2,2,2) f32, syndrome (128, 4*4096) i32,
// out (128,8,2,2,2) f32 = mean over the 4096 sites after 3 rounds of
// conditional 64-permutations.
#define BATCH 128

// ws byte offsets for flag arrays
#define OFF_FZ0 0
#define OFF_FZ1 (OFF_FZ0 + BATCH * 256)
#define OFF_FZ2 (OFF_FZ1 + BATCH * 256)
#define OFF_FX0 (OFF_FZ2 + BATCH * 256)
#define OFF_FX1 (OFF_FX0 + BATCH * 16)
#define OFF_FX2 (OFF_FX1 + BATCH * 16)

// ---- permutation algebra ---------------------------------------------------
// Flat in-site index u = s*8 + a*4 + b*2 + c  (s: 3 bits [5:3], a=bit2, b=bit1, c=bit0)
// _swap_stabilizers as an index map S: out[o] = in[S(o)],
//   S(o) = A(PERM8[o>>3]*8 + (o&7)),  A(q) = (q&7)<<3 | q2<<2 | q3<<1 | q4... see below.
__device__ __forceinline__ int A_of(int o) {
    return ((o & 7) << 3) | (((o >> 3) & 1) << 2) | (((o >> 4) & 1) << 1) | ((o >> 5) & 1);
}
__device__ __forceinline__ int S_of(int o) {
    // PERM8 = {0,6,2,4,3,5,1,7} packed 3 bits each
    const unsigned P = (0u) | (6u << 3) | (2u << 6) | (4u << 9) | (3u << 12) |
                       (5u << 15) | (1u << 18) | (7u << 21);
    int s = (int)((P >> (3 * (o >> 3))) & 7u);
    return A_of((s << 3) | (o & 7));
}

// flags from a 16-entry parity row r: f[0] = xor(all); f[t>=1] = r[0] ^ xor(r[17-t..15])
__device__ __forceinline__ unsigned flag16(const unsigned char* r, int pos) {
    unsigned f;
    if (pos == 0) {
        f = 0;
#pragma unroll
        for (int w = 0; w < 16; ++w) f ^= r[w];
    } else {
        f = r[0];
        for (int w = 17 - pos; w <= 15; ++w) f ^= r[w];
    }
    return f & 1u;
}

// ---- kernel 1: per-batch syndrome parity flags ----------------------------
__global__ __launch_bounds__(256) void k_flags(const int* __restrict__ syn,
                                               unsigned char* __restrict__ ws) {
    int b = blockIdx.x;
    int t = threadIdx.x;
    const int* base = syn + (size_t)b * 16384;
    const int* z  = base;
    const int* x0 = base + 4096;
    const int* x1 = base + 8192;
    const int* x2 = base + 12288;

    __shared__ unsigned char sp0[256], sp1[256], sp2[256];  // z parity surfaces
    __shared__ unsigned char tA[256], tB[256], tC[256];     // x-channel partials
    __shared__ unsigned char g0[16], g1[16], g2[16];

    int dhi = t >> 4, dlo = t & 15;
    unsigned p;
    // sp0[(d2,d3)] = xor_{d1} z
    p = 0; for (int d1 = 0; d1 < 16; ++d1) p ^= (unsigned)z[d1 * 256 + t];            sp0[t] = p & 1;
    // sp1[(d1,d3)] = xor_{d2} z
    p = 0; for (int d2 = 0; d2 < 16; ++d2) p ^= (unsigned)z[dhi * 256 + d2 * 16 + dlo]; sp1[t] = p & 1;
    // sp2[(d1,d2)] = xor_{d3} z
    p = 0; for (int d3 = 0; d3 < 16; ++d3) p ^= (unsigned)z[dhi * 256 + dlo * 16 + d3]; sp2[t] = p & 1;
    // tA[(d2,d3)] = xor_{d1} x0
    p = 0; for (int d1 = 0; d1 < 16; ++d1) p ^= (unsigned)x0[d1 * 256 + t];           tA[t] = p & 1;
    // tB[(d1,d2)] = xor_{d3} x1
    p = 0; for (int d3 = 0; d3 < 16; ++d3) p ^= (unsigned)x1[dhi * 256 + dlo * 16 + d3]; tB[t] = p & 1;
    // tC[(d1,d2)] = xor_{d3} x2
    p = 0; for (int d3 = 0; d3 < 16; ++d3) p ^= (unsigned)x2[dhi * 256 + dlo * 16 + d3]; tC[t] = p & 1;
    __syncthreads();

    if (t < 16) {
        unsigned q = 0;                       // cp0[d3] = xor_{d2} tA ; surf shifted by 1 (roll)
        for (int d2 = 0; d2 < 16; ++d2) q ^= tA[d2 * 16 + t];
        g0[(t + 1) & 15] = q & 1;
    } else if (t < 32) {
        int d1 = t - 16; unsigned q = 0;      // g1[d1] = xor_{d2,d3} x1
        for (int d2 = 0; d2 < 16; ++d2) q ^= tB[d1 * 16 + d2];
        g1[d1] = q & 1;
    } else if (t < 48) {
        int d2 = t - 32; unsigned q = 0;      // g2[d2] = xor_{d1,d3} x2
        for (int d1 = 0; d1 < 16; ++d1) q ^= tC[d1 * 16 + d2];
        g2[d2] = q & 1;
    }
    __syncthreads();

    // fz layouts: [row*16 + pos]
    ws[OFF_FZ0 + b * 256 + t] = (unsigned char)flag16(&sp0[dhi * 16], dlo); // row=d2
    ws[OFF_FZ1 + b * 256 + t] = (unsigned char)flag16(&sp1[dhi * 16], dlo); // row=d1
    ws[OFF_FZ2 + b * 256 + t] = (unsigned char)flag16(&sp2[dhi * 16], dlo); // row=d1
    if (t < 16) {
        ws[OFF_FX0 + b * 16 + t] = (unsigned char)flag16(g0, t);
        ws[OFF_FX1 + b * 16 + t] = (unsigned char)flag16(g1, t);
        ws[OFF_FX2 + b * 16 + t] = (unsigned char)flag16(g2, t);
    }
}

// ---- kernel 2: streaming pass over x ---------------------------------------
// grid (16, 128): block (i0, b) handles the 256 sites with that i0.
__global__ __launch_bounds__(256) void k_main(const float* __restrict__ x,
                                              const unsigned char* __restrict__ ws,
                                              float* __restrict__ out) {
    __shared__ unsigned char T[4096];        // T[m][v] = source element for mask m, dest v
    __shared__ unsigned char fz0[256], fz1[256], fz2[256];
    __shared__ unsigned char fx0[16], fx1[16], fx2[16];
    __shared__ unsigned char mArr[256];      // maskcode per site (j0*16+k0)
    __shared__ unsigned char Ctab[3][64];    // C_axis index maps
    __shared__ float red[256];

    int b  = blockIdx.y;
    int i0 = blockIdx.x;
    int t  = threadIdx.x;

    fz0[t] = ws[OFF_FZ0 + b * 256 + t];
    fz1[t] = ws[OFF_FZ1 + b * 256 + t];
    fz2[t] = ws[OFF_FZ2 + b * 256 + t];
    if (t < 16) {
        fx0[t] = ws[OFF_FX0 + b * 16 + t];
        fx1[t] = ws[OFF_FX1 + b * 16 + t];
        fx2[t] = ws[OFF_FX2 + b * 16 + t];
    }
    if (t < 192) {
        int ax = t >> 6, o = t & 63;
        int bit = 4 >> ax;                    // cand roll flips bit (2-ax): 4,2,1
        Ctab[ax][o] = (unsigned char)S_of(S_of(o) ^ bit);
    }
    __syncthreads();

    {   // maskcode per site of this i0-slab
        int j0 = t >> 4, k0 = t & 15;
        unsigned m = (unsigned)fz0[k0 * 16 + j0]
                   | ((unsigned)fx0[k0] << 1)
                   | ((unsigned)fz1[i0 * 16 + k0] << 2)
                   | ((unsigned)fx1[i0] << 3)
                   | ((unsigned)fz2[j0 * 16 + i0] << 4)
                   | ((unsigned)fx2[j0] << 5);
        mArr[t] = (unsigned char)m;
    }
    // build T: out[o] = in[p1(p2(...p6(o)))], last step applied first to o
    for (int idx = t; idx < 4096; idx += 256) {
        int m = idx >> 6, v = idx & 63;
        int src = v;
        if (m & 32) src ^= 4;                 // X2: flip 'a'
        if (m & 16) src = Ctab[2][src];       // C2
        if (m & 8)  src ^= 2;                 // X1: flip 'b'
        if (m & 4)  src = Ctab[1][src];       // C1
        if (m & 2)  src ^= 1;                 // X0: flip 'c'
        if (m & 1)  src = Ctab[0][src];       // C0
        T[idx] = (unsigned char)src;
    }
    __syncthreads();

    int wave = t >> 6, v = t & 63;
    const float* xb = x + (((size_t)b * 4096 + (size_t)i0 * 256) << 6);
    float acc = 0.f;
#pragma unroll 4
    for (int it = 0; it < 64; ++it) {
        int sl = wave * 64 + it;                          // site within slab
        float val = xb[((size_t)sl << 6) + v];            // coalesced 256B/wave
        int m   = mArr[sl];                               // wave-uniform broadcast
        int src = T[(m << 6) | v];                        // conflict-free byte row
        int pulled = __builtin_amdgcn_ds_bpermute(src << 2, __float_as_int(val));
        acc += __int_as_float(pulled);
    }
    red[t] = acc;
    __syncthreads();
    if (t < 64) {
        float s4 = red[t] + red[t + 64] + red[t + 128] + red[t + 192];
        atomicAdd(out + b * 64 + t, s4 * (1.0f / 4096.0f));
    }
}

extern "C" void kernel_launch(void* const* d_in, const int* in_sizes, int n_in,
                              void* d_out, int out_size, void* d_ws, size_t ws_size,
                              hipStream_t stream) {
    const float* x   = (const float*)d_in[0];
    const int*   syn = (const int*)d_in[1];
    float* out = (float*)d_out;
    unsigned char* ws = (unsigned char*)d_ws;

    hipMemsetAsync(d_out, 0, (size_t)out_size * sizeof(float), stream);
    k_flags<<<BATCH, 256, 0, stream>>>(syn, ws);
    k_main<<<dim3(16, BATCH), 256, 0, stream>>>(x, ws, out);
}

// Round 2
// 199.234 us; speedup vs baseline: 1.0188x; 1.0188x over previous
//
#include <hip/hip_runtime.h>
#include <stdint.h>

#define BATCH 128

// ws byte offsets for flag arrays
#define OFF_FZ0 0
#define OFF_FZ1 (OFF_FZ0 + BATCH * 256)
#define OFF_FZ2 (OFF_FZ1 + BATCH * 256)
#define OFF_FX0 (OFF_FZ2 + BATCH * 256)
#define OFF_FX1 (OFF_FX0 + BATCH * 16)
#define OFF_FX2 (OFF_FX1 + BATCH * 16)

// ---- permutation algebra (unchanged from passing R1 kernel) ----------------
__device__ __forceinline__ int A_of(int o) {
    return ((o & 7) << 3) | (((o >> 3) & 1) << 2) | (((o >> 4) & 1) << 1) | ((o >> 5) & 1);
}
__device__ __forceinline__ int S_of(int o) {
    const unsigned P = (0u) | (6u << 3) | (2u << 6) | (4u << 9) | (3u << 12) |
                       (5u << 15) | (1u << 18) | (7u << 21);
    int s = (int)((P >> (3 * (o >> 3))) & 7u);
    return A_of((s << 3) | (o & 7));
}

__device__ __forceinline__ unsigned flag16(const unsigned char* r, int pos) {
    unsigned f;
    if (pos == 0) {
        f = 0;
#pragma unroll
        for (int w = 0; w < 16; ++w) f ^= r[w];
    } else {
        f = r[0];
        for (int w = 17 - pos; w <= 15; ++w) f ^= r[w];
    }
    return f & 1u;
}

// ---- kernel 1: per-batch syndrome parity flags, 6-way job-parallel ---------
// grid (BATCH, 6); same math as the R1-passing kernel, one job per block.
__global__ __launch_bounds__(256) void k_flags(const int* __restrict__ syn,
                                               unsigned char* __restrict__ ws) {
    int b = blockIdx.x, job = blockIdx.y, t = threadIdx.x;
    int dhi = t >> 4, dlo = t & 15;
    const int* base = syn + (size_t)b * 16384;
    __shared__ unsigned char sp[256];
    __shared__ unsigned char g[16];
    unsigned p = 0;

    if (job == 0) {                       // fz0 from z, parity over d1
        const int* z = base;
#pragma unroll
        for (int d1 = 0; d1 < 16; ++d1) p ^= (unsigned)z[d1 * 256 + t];
        sp[t] = p & 1;
        __syncthreads();
        ws[OFF_FZ0 + b * 256 + t] = (unsigned char)flag16(&sp[dhi * 16], dlo);
    } else if (job == 1) {                // fz1 from z, parity over d2
        const int* z = base;
#pragma unroll
        for (int d2 = 0; d2 < 16; ++d2) p ^= (unsigned)z[dhi * 256 + d2 * 16 + dlo];
        sp[t] = p & 1;
        __syncthreads();
        ws[OFF_FZ1 + b * 256 + t] = (unsigned char)flag16(&sp[dhi * 16], dlo);
    } else if (job == 2) {                // fz2 from z, parity over d3
        const int* z = base;
#pragma unroll
        for (int d3 = 0; d3 < 16; ++d3) p ^= (unsigned)z[dhi * 256 + dlo * 16 + d3];
        sp[t] = p & 1;
        __syncthreads();
        ws[OFF_FZ2 + b * 256 + t] = (unsigned char)flag16(&sp[dhi * 16], dlo);
    } else if (job == 3) {                // fx0 from x0
        const int* x0 = base + 4096;
#pragma unroll
        for (int d1 = 0; d1 < 16; ++d1) p ^= (unsigned)x0[d1 * 256 + t];
        sp[t] = p & 1;                    // t = (d2,d3)
        __syncthreads();
        if (t < 16) {
            unsigned q = 0;
            for (int d2 = 0; d2 < 16; ++d2) q ^= sp[d2 * 16 + t];
            g[(t + 1) & 15] = q & 1;      // roll shift 1
        }
        __syncthreads();
        if (t < 16) ws[OFF_FX0 + b * 16 + t] = (unsigned char)flag16(g, t);
    } else if (job == 4) {                // fx1 from x1
        const int* x1 = base + 8192;
#pragma unroll
        for (int d3 = 0; d3 < 16; ++d3) p ^= (unsigned)x1[dhi * 256 + dlo * 16 + d3];
        sp[t] = p & 1;                    // t = (d1,d2)
        __syncthreads();
        if (t < 16) {
            unsigned q = 0;
            for (int d2 = 0; d2 < 16; ++d2) q ^= sp[t * 16 + d2];
            g[t] = q & 1;
        }
        __syncthreads();
        if (t < 16) ws[OFF_FX1 + b * 16 + t] = (unsigned char)flag16(g, t);
    } else {                              // fx2 from x2
        const int* x2 = base + 12288;
#pragma unroll
        for (int d3 = 0; d3 < 16; ++d3) p ^= (unsigned)x2[dhi * 256 + dlo * 16 + d3];
        sp[t] = p & 1;                    // t = (d1,d2)
        __syncthreads();
        if (t < 16) {
            unsigned q = 0;
            for (int d1 = 0; d1 < 16; ++d1) q ^= sp[d1 * 16 + t];
            g[t] = q & 1;
        }
        __syncthreads();
        if (t < 16) ws[OFF_FX2 + b * 16 + t] = (unsigned char)flag16(g, t);
    }
}

// ---- async global->LDS DMA (width 16) --------------------------------------
typedef const __attribute__((address_space(1))) uint32_t glob_u32;
typedef __attribute__((address_space(3))) uint32_t lds_u32;
__device__ __forceinline__ void dma16(const float* g, float* l) {
    // lane i lands at l + i*16B; g is the per-lane global address.
    __builtin_amdgcn_global_load_lds((glob_u32*)g, (lds_u32*)l, 16, 0, 0);
}

// ---- kernel 2: streaming pass with DMA staging + LDS permuted reads --------
// grid (16, BATCH): block (i0, b) handles 256 sites (64 KB of x), in 4 chunks
// of 64 sites, double-buffered. Each wave stages and consumes its own 16
// sites per chunk; barrier pipeline overlaps stage(c+1) with consume(c).
__global__ __launch_bounds__(256) void k_main(const float* __restrict__ x,
                                              const unsigned char* __restrict__ ws,
                                              float* __restrict__ out) {
    __shared__ float buf[2][64 * 64];        // 32 KB double buffer
    __shared__ unsigned char T[4096];        // T[m][v] = source element
    __shared__ unsigned char fz0[256], fz1[256], fz2[256];
    __shared__ unsigned char fx0[16], fx1[16], fx2[16];
    __shared__ unsigned char mArr[256];
    __shared__ unsigned char Ctab[3][64];
    __shared__ float red[256];

    int b  = blockIdx.y;
    int i0 = blockIdx.x;
    int t  = threadIdx.x;
    int w  = t >> 6, v = t & 63;

    const float* xb = x + (((size_t)b * 4096 + (size_t)i0 * 256) << 6);

    // issue chunk-0 DMA first so it overlaps the table setup below
    {
        const float* gsrc = xb + ((w * 16) << 6) + (v << 2);
        float* ldst = &buf[0][(w * 16) << 6];
        dma16(gsrc,       ldst);
        dma16(gsrc + 256, ldst + 256);
        dma16(gsrc + 512, ldst + 512);
        dma16(gsrc + 768, ldst + 768);
    }

    fz0[t] = ws[OFF_FZ0 + b * 256 + t];
    fz1[t] = ws[OFF_FZ1 + b * 256 + t];
    fz2[t] = ws[OFF_FZ2 + b * 256 + t];
    if (t < 16) {
        fx0[t] = ws[OFF_FX0 + b * 16 + t];
        fx1[t] = ws[OFF_FX1 + b * 16 + t];
        fx2[t] = ws[OFF_FX2 + b * 16 + t];
    }
    if (t < 192) {
        int ax = t >> 6, o = t & 63;
        int bit = 4 >> ax;
        Ctab[ax][o] = (unsigned char)S_of(S_of(o) ^ bit);
    }
    __syncthreads();                          // flags+Ctab ready (also drains chunk0 DMA)

    {   // maskcode per site (j0*16+k0), identical to R1
        int j0 = t >> 4, k0 = t & 15;
        unsigned m = (unsigned)fz0[k0 * 16 + j0]
                   | ((unsigned)fx0[k0] << 1)
                   | ((unsigned)fz1[i0 * 16 + k0] << 2)
                   | ((unsigned)fx1[i0] << 3)
                   | ((unsigned)fz2[j0 * 16 + i0] << 4)
                   | ((unsigned)fx2[j0] << 5);
        mArr[t] = (unsigned char)m;
    }
    for (int idx = t; idx < 4096; idx += 256) {
        int m = idx >> 6, vv = idx & 63;
        int src = vv;
        if (m & 32) src ^= 4;
        if (m & 16) src = Ctab[2][src];
        if (m & 8)  src ^= 2;
        if (m & 4)  src = Ctab[1][src];
        if (m & 2)  src ^= 1;
        if (m & 1)  src = Ctab[0][src];
        T[idx] = (unsigned char)src;
    }
    __syncthreads();                          // T + mArr ready

    float acc = 0.f;
    const unsigned char* Trow = T;            // T[(m<<6)|v]
#pragma unroll
    for (int c = 0; c < 4; ++c) {
        if (c < 3) {                          // prefetch next chunk
            const float* gsrc = xb + (((c + 1) * 64 + w * 16) << 6) + (v << 2);
            float* ldst = &buf[(c + 1) & 1][(w * 16) << 6];
            dma16(gsrc,       ldst);
            dma16(gsrc + 256, ldst + 256);
            dma16(gsrc + 512, ldst + 512);
            dma16(gsrc + 768, ldst + 768);
        }
        // consume this wave's 16 sites of chunk c
        const float* bufw = &buf[c & 1][(w * 16) << 6];
        int sl_base = c * 64 + w * 16;
#pragma unroll
        for (int it = 0; it < 16; ++it) {
            int m   = mArr[sl_base + it];                 // broadcast ds_read_u8
            int src = Trow[(m << 6) | v];                 // 64B row, byte read
            acc += bufw[(it << 6) | src];                 // permuted dword read, 2 lanes/bank
        }
        __syncthreads();                      // protect dbuf reuse; drains prefetch
    }

    red[t] = acc;
    __syncthreads();
    if (t < 64) {
        float s4 = red[t] + red[t + 64] + red[t + 128] + red[t + 192];
        atomicAdd(out + b * 64 + t, s4 * (1.0f / 4096.0f));
    }
}

extern "C" void kernel_launch(void* const* d_in, const int* in_sizes, int n_in,
                              void* d_out, int out_size, void* d_ws, size_t ws_size,
                              hipStream_t stream) {
    const float* x   = (const float*)d_in[0];
    const int*   syn = (const int*)d_in[1];
    float* out = (float*)d_out;
    unsigned char* ws = (unsigned char*)d_ws;

    hipMemsetAsync(d_out, 0, (size_t)out_size * sizeof(float), stream);
    k_flags<<<dim3(BATCH, 6), 256, 0, stream>>>(syn, ws);
    k_main<<<dim3(16, BATCH), 256, 0, stream>>>(x, ws, out);
}